// Round 2
// baseline (132.422 us; speedup 1.0000x reference)
//
#include <hip/hip_runtime.h>

// Problem constants (reference: x = [8, 4096, 85] fp32)
constexpr int BS = 8;
constexpr int N  = 4096;
constexpr int F  = 85;
constexpr int NC = 80;          // classes = F - 5
constexpr float CONF_T = 0.65f;
constexpr float NMS_T  = 0.55f;
constexpr int MC   = 96;        // per-(batch,class) member cap (mean ~18, max ~33)
constexpr int SEGR = 32;        // rows per prep block (R1: 128 -> 32 for occupancy)
constexpr int BPB  = N / SEGR;  // prep blocks per batch = 128

// key = (~bits(conf))<<19 | idx<<7 | cls.  Ascending key order == (conf desc,
// idx asc) == the reference's stable argsort (idx unique -> cls bits never
// affect order).
//
// R1 change vs 92.0us baseline: rank is permutation-invariant (exact rank via
// full-key compares), so prep compacts keys with per-wave atomicAdd slot
// reservation into a flat per-batch array -> no segment counts, no prefix
// scan, no predicated pack in rank. Prep: 1024 blocks (4/CU, 16 waves/CU)
// instead of 256 (1 wave/SIMD — zero latency hiding), argmax split 8-way/row
// with shfl_xor (value, first-idx) reduce.

// ---------------- K1: prep (LDS-staged read, 8-way argmax, atomic compact) ----
__global__ __launch_bounds__(256) void prep_kernel(
        const float* __restrict__ x,
        unsigned long long* __restrict__ gkeys,   // [BS][N] compact per batch
        float4* __restrict__ vbox,                // [BS*N] by original idx (valid only)
        float2* __restrict__ vco,                 // (obj, conf)
        int* __restrict__ cnt,                    // [BS], pre-zeroed
        float4* __restrict__ out) {
    __shared__ __align__(16) float sx[SEGR * F];  // 10,880 B -> 4+ blocks/CU
    const int tid = threadIdx.x, blk = blockIdx.x;
    const int row0 = blk * SEGR;
    const int b = blk >> 7;                       // blk / BPB
    // coalesced staging: 680 float4 per block, 3 rounds
    const float4* src = (const float4*)(x + (size_t)row0 * F);
    float4* dst = (float4*)sx;
    constexpr int NV4 = SEGR * F / 4;             // 680
    for (int i = tid; i < NV4; i += 256) dst[i] = src[i];
    // zero this block's 32 output rows (2 float4 each, covered once per grid)
    if (tid < SEGR * 2)
        out[(size_t)row0 * 2 + tid] = make_float4(0.f, 0.f, 0.f, 0.f);
    __syncthreads();

    // split argmax: thread (r, h) scans classes h*10..h*10+9 of row r
    const int r = tid >> 3, h = tid & 7;
    float best; int bidx;
    {
        const float* p = sx + r * F + 5 + h * 10;
        float bv = p[0]; int bi = 0;
        #pragma unroll
        for (int c = 1; c < 10; ++c) {
            float v = p[c];
            if (v > bv) { bv = v; bi = c; }       // strict >: first max in chunk
        }
        best = bv; bidx = bi + h * 10;
    }
    // reduce across the 8 h-lanes (same wave, xor in low 3 bits of lane)
    #pragma unroll
    for (int d = 1; d < 8; d <<= 1) {
        float ov = __shfl_xor(best, d);
        int   oi = __shfl_xor(bidx, d);
        if (ov > best || (ov == best && oi < bidx)) { best = ov; bidx = oi; }
    }   // == global max with smallest attaining idx == jnp.argmax (first max)

    bool valid = false;
    unsigned long long key = 0;
    if (h == 0) {
        const float* p = sx + r * F;
        float obj = p[4];
        valid = obj > CONF_T;
        const int t = row0 + r;
        if (valid) {
            float cx = p[0], cy = p[1], w = p[2], hh = p[3];
            vbox[t] = make_float4(cx - w * 0.5f, cy - hh * 0.5f,
                                  cx + w * 0.5f, cy + hh * 0.5f);
            vco[t]  = make_float2(obj, best);
            key = ((unsigned long long)(~__float_as_uint(best)) << 19)
                | ((unsigned long long)(unsigned)(t & (N - 1)) << 7)
                | (unsigned)bidx;
        }
    }
    // per-wave slot reservation; order within gkeys is irrelevant to rank
    unsigned long long mask = __ballot(valid);
    int nw = __popcll(mask);                      // wave-uniform
    if (nw) {
        const int lane = tid & 63;
        int base;
        if (lane == 0) base = atomicAdd(&cnt[b], nw);
        base = __shfl(base, 0);
        if (valid) {
            int slot = base + __popcll(mask & ((1ull << lane) - 1ull));
            gkeys[((size_t)b << 12) + slot] = key;
        }
    }
}

// ---------------- K2: rank-by-count over valid keys only ----------------
// grid (64, BS) x 256. Block ranks 64 compact boxes; 4 threads each scan a
// quarter of the packed keys via b128 broadcast LDS reads. Pack is now a
// straight coalesced copy (prep's atomic compaction).
__global__ __launch_bounds__(256) void rank_kernel(
        const unsigned long long* __restrict__ gkeys,
        const float4* __restrict__ vbox,
        const float2* __restrict__ vco,
        const int* __restrict__ cnt,
        float4* __restrict__ rbox,
        float2* __restrict__ rco,
        int* __restrict__ rcls) {
    __shared__ __align__(16) unsigned long long sk[N + 2];
    __shared__ int part[256];
    const int b = blockIdx.y, tid = threadIdx.x;
    const int nv = cnt[b];
    const int c0 = blockIdx.x * 64;
    if (c0 >= nv) return;                          // block-uniform exit

    const unsigned long long* kb = gkeys + ((size_t)b << 12);
    for (int i = tid; i < nv; i += 256) sk[i] = kb[i];
    if (tid == 0) { sk[nv] = ~0ull; sk[nv + 1] = ~0ull; }  // pair-read pad
    __syncthreads();

    const int li = tid & 63, q = tid >> 6;
    const int bi = c0 + li;
    const bool active = bi < nv;
    const unsigned long long myk = active ? sk[bi] : 0;
    const int P = (nv + 1) >> 1;                   // u64 pairs
    const int j0 = (P * q) >> 2, j1 = (P * (q + 1)) >> 2;
    const ulonglong2* skp = (const ulonglong2*)sk;
    int cr = 0;
    for (int j = j0; j < j1; ++j) {                // b128 broadcast reads
        ulonglong2 kk = skp[j];
        cr += (kk.x < myk) ? 1 : 0;
        cr += (kk.y < myk) ? 1 : 0;
    }
    part[tid] = cr;
    __syncthreads();
    if (q == 0 && active) {
        int rank = part[li] + part[li + 64] + part[li + 128] + part[li + 192];
        int idx = (int)((myk >> 7) & (N - 1));
        int s = (b << 12) + idx;
        int d = (b << 12) + rank;                  // exact stable rank
        rbox[d] = vbox[s];
        rco[d]  = vco[s];
        rcls[d] = (int)(myk & 127u);
    }
}

// ---------------- K3: per-(batch,class) greedy NMS + emit ----------------
// grid (NC, BS), one wave. 32 unrolled independent rcls chunk loads (one
// exposed latency) -> ballot compaction of member ranks; box gather in <=2
// scattered rounds; wave-synchronous greedy (reference IoU); direct row emit.
__global__ __launch_bounds__(64) void nms_kernel(
        const float4* __restrict__ rbox,
        const float2* __restrict__ rco,
        const int* __restrict__ rcls,
        const int* __restrict__ cnt,
        float4* __restrict__ out) {
    __shared__ float4 sbox[MC];
    __shared__ unsigned short srank[MC];
    __shared__ unsigned char srem[MC];
    const int c = blockIdx.x, b = blockIdx.y, lane = threadIdx.x;
    const int bN = b << 12;
    const int nv = cnt[b];
    constexpr int MAXCH = 32;                      // covers nv <= 2048 fast path

    int cv[MAXCH];
    #pragma unroll
    for (int ch = 0; ch < MAXCH; ++ch) {           // independent coalesced loads
        int rn = ch * 64 + lane;
        cv[ch] = rcls[bN + (rn < nv ? rn : 0)];    // clamped, in-bounds
    }
    int n = 0;
    #pragma unroll
    for (int ch = 0; ch < MAXCH; ++ch) {
        int rn = ch * 64 + lane;
        bool member = (rn < nv) && (cv[ch] == c);
        unsigned long long mb = __ballot(member);
        if (member) {
            int pos = n + __popcll(mb & ((1ull << lane) - 1ull));
            if (pos < MC) srank[pos] = (unsigned short)rn;
        }
        n += __popcll(mb);
    }
    for (int base = MAXCH * 64; base < nv; base += 64) {   // rare tail (nv>2048)
        int rn = base + lane;
        bool member = (rn < nv) && (rcls[bN + (rn < nv ? rn : 0)] == c);
        unsigned long long mb = __ballot(member);
        if (member) {
            int pos = n + __popcll(mb & ((1ull << lane) - 1ull));
            if (pos < MC) srank[pos] = (unsigned short)rn;
        }
        n += __popcll(mb);
    }
    if (n > MC) n = MC;
    const int m = n;

    // gather member boxes (rank order == conf-desc order), <=2 scattered rounds
    for (int i = lane; i < m; i += 64) {
        sbox[i] = rbox[bN + srank[i]];
        srem[i] = 0;
    }

    // single wave owns the LDS: wave-synchronous, no barriers needed
    for (int i = 0; i < m; ++i) {
        if (srem[i]) continue;                     // same LDS address: uniform
        float4 bi4 = sbox[i];
        float ai = (bi4.z - bi4.x) * (bi4.w - bi4.y);
        for (int j = i + 1 + lane; j < m; j += 64) {
            if (!srem[j]) {
                float4 bj = sbox[j];
                float ix1 = fmaxf(bi4.x, bj.x);
                float iy1 = fmaxf(bi4.y, bj.y);
                float ix2 = fminf(bi4.z, bj.z);
                float iy2 = fminf(bi4.w, bj.w);
                float inter = fmaxf(ix2 - ix1, 0.0f) * fmaxf(iy2 - iy1, 0.0f);
                float aj = (bj.z - bj.x) * (bj.w - bj.y);
                float iou = inter / (ai + aj - inter + 1e-16f);
                if (iou > NMS_T) srem[j] = 1;
            }
        }
    }
    for (int j = lane; j < m; j += 64) {
        if (!srem[j]) {
            int rr = srank[j];
            float4 bq = sbox[j];
            float2 oc = rco[bN + rr];
            float4* o = out + (size_t)(bN + rr) * 2;
            o[0] = make_float4((float)b, bq.x, bq.y, bq.z);
            o[1] = make_float4(bq.w, oc.x, oc.y, (float)c);
        }
    }
}

extern "C" void kernel_launch(void* const* d_in, const int* in_sizes, int n_in,
                              void* d_out, int out_size, void* d_ws, size_t ws_size,
                              hipStream_t stream) {
    const float* x = (const float*)d_in[0];
    float4* out = (float4*)d_out;

    char* ws = (char*)d_ws;
    size_t off = 0;
    auto alloc = [&](size_t bytes) { char* p = ws + off; off += (bytes + 255) & ~255ull; return p; };
    unsigned long long* gkeys = (unsigned long long*)alloc(BS * N * 8);  // 256 KB
    float4* vbox = (float4*)alloc(BS * N * 16);                           // 512 KB
    float2* vco  = (float2*)alloc(BS * N * 8);                            // 256 KB
    float4* rbox = (float4*)alloc(BS * N * 16);                           // 512 KB
    float2* rco  = (float2*)alloc(BS * N * 8);                            // 256 KB
    int*    rcls = (int*)alloc(BS * N * 4);                               // 128 KB
    int*    cnt  = (int*)alloc(BS * 4);                                   // 32 B

    hipMemsetAsync(cnt, 0, BS * sizeof(int), stream);                     // atomic base
    prep_kernel<<<BS * N / SEGR, 256, 0, stream>>>(x, gkeys, vbox, vco, cnt, out);
    rank_kernel<<<dim3(64, BS), 256, 0, stream>>>(gkeys, vbox, vco, cnt,
                                                  rbox, rco, rcls);
    nms_kernel<<<dim3(NC, BS), 64, 0, stream>>>(rbox, rco, rcls, cnt, out);
}

// Round 3
// 90.642 us; speedup vs baseline: 1.4609x; 1.4609x over previous
//
#include <hip/hip_runtime.h>

// Problem constants (reference: x = [8, 4096, 85] fp32)
constexpr int BS = 8;
constexpr int N  = 4096;
constexpr int F  = 85;
constexpr int NC = 80;          // classes = F - 5
constexpr float CONF_T = 0.65f;
constexpr float NMS_T  = 0.55f;
constexpr int MC   = 96;        // per-(batch,class) member cap (mean ~18, max ~33)
constexpr int SEGR = 32;        // rows per prep block / segment
constexpr int SEGS = N / SEGR;  // segments per batch = 128

// key = (~bits(conf))<<19 | idx<<7 | cls.  Ascending key order == (conf desc,
// idx asc) == the reference's stable argsort (idx unique -> cls bits never
// affect order). Only VALID boxes get keys (segmented compact layout).
//
// R2: R1's per-wave atomicAdd slot reservation (4096 device-scope atomics on
// one cache line) serialized the whole grid: prep=50us, VALUBusy=1.4%.
// Reverted to deterministic segmented compaction (measured fine in the 92us
// baseline): zero global atomics. Kept R1's 1024-block occupancy + 8-way
// shfl argmax. rank regains a cheap 128-seg scan (1 wave, 2 counts/lane).

// ---------------- K1: prep (LDS-staged read, 8-way argmax, segment compact) ----
__global__ __launch_bounds__(256) void prep_kernel(
        const float* __restrict__ x,
        unsigned long long* __restrict__ gkeys,   // [BS][SEGS*32] segmented
        float4* __restrict__ vbox,                // [BS*N] by original idx (valid only)
        float2* __restrict__ vco,                 // (obj, conf)
        int* __restrict__ cntblk,                 // [BS*SEGS]
        float4* __restrict__ out) {
    __shared__ __align__(16) float sx[SEGR * F];  // 10,880 B
    __shared__ int wq[4];
    const int tid = threadIdx.x, blk = blockIdx.x;
    const int row0 = blk * SEGR;
    const int b = blk >> 7;                       // blk / SEGS
    // coalesced staging: 680 float4 per block, 3 rounds
    const float4* src = (const float4*)(x + (size_t)row0 * F);
    float4* dst = (float4*)sx;
    constexpr int NV4 = SEGR * F / 4;             // 680
    for (int i = tid; i < NV4; i += 256) dst[i] = src[i];
    // zero this block's 32 output rows (2 float4 each, covered once per grid)
    if (tid < SEGR * 2)
        out[(size_t)row0 * 2 + tid] = make_float4(0.f, 0.f, 0.f, 0.f);
    __syncthreads();

    // split argmax: thread (r, h) scans classes h*10..h*10+9 of row r
    const int r = tid >> 3, h = tid & 7;
    float best; int bidx;
    {
        const float* p = sx + r * F + 5 + h * 10;
        float bv = p[0]; int bi = 0;
        #pragma unroll
        for (int c = 1; c < 10; ++c) {
            float v = p[c];
            if (v > bv) { bv = v; bi = c; }       // strict >: first max in chunk
        }
        best = bv; bidx = bi + h * 10;
    }
    // reduce across the 8 h-lanes (same wave, xor in low 3 bits of lane)
    #pragma unroll
    for (int d = 1; d < 8; d <<= 1) {
        float ov = __shfl_xor(best, d);
        int   oi = __shfl_xor(bidx, d);
        if (ov > best || (ov == best && oi < bidx)) { best = ov; bidx = oi; }
    }   // == global max with smallest attaining idx == jnp.argmax (first max)

    bool valid = false;
    unsigned long long key = 0;
    if (h == 0) {
        const float* p = sx + r * F;
        float obj = p[4];
        valid = obj > CONF_T;
        const int t = row0 + r;
        if (valid) {
            float cx = p[0], cy = p[1], w = p[2], hh = p[3];
            vbox[t] = make_float4(cx - w * 0.5f, cy - hh * 0.5f,
                                  cx + w * 0.5f, cy + hh * 0.5f);
            vco[t]  = make_float2(obj, best);
            key = ((unsigned long long)(~__float_as_uint(best)) << 19)
                | ((unsigned long long)(unsigned)(t & (N - 1)) << 7)
                | (unsigned)bidx;
        }
    }
    // deterministic block-local compaction into this block's 32-slot segment
    const int lane = tid & 63, w = tid >> 6;
    unsigned long long mask = __ballot(valid);
    if (lane == 0) wq[w] = __popcll(mask);
    __syncthreads();
    int base = 0;
    for (int i = 0; i < w; ++i) base += wq[i];
    if (valid) {
        int slot = base + __popcll(mask & ((1ull << lane) - 1ull));
        gkeys[((size_t)b << 12) + ((blk & (SEGS - 1)) << 5) + slot] = key;
    }
    if (tid == 0) cntblk[blk] = wq[0] + wq[1] + wq[2] + wq[3];
}

// ---------------- K2: rank-by-count over valid keys only ----------------
// grid (64, BS) x 256. Block ranks 64 compact boxes; 4 threads each scan a
// quarter of the packed keys via b128 broadcast LDS reads. Segment pack is a
// flat predicated loop; 128-seg prefix scan done by one wave (2 counts/lane
// + shfl_up inclusive scan). Writes cnt[b]=nv for nms.
__global__ __launch_bounds__(256) void rank_kernel(
        const unsigned long long* __restrict__ gkeys,
        const float4* __restrict__ vbox,
        const float2* __restrict__ vco,
        const int* __restrict__ cntblk,
        float4* __restrict__ rbox,
        float2* __restrict__ rco,
        int* __restrict__ rcls,
        int* __restrict__ cnt) {
    __shared__ __align__(16) unsigned long long sk[N + 2];
    __shared__ int scnt[SEGS];
    __shared__ int soff[SEGS];
    __shared__ int snv;
    __shared__ int part[256];
    const int b = blockIdx.y, tid = threadIdx.x;
    if (tid < 64) {                                // one wave scans 128 counts
        int v0 = cntblk[b * SEGS + 2 * tid];
        int v1 = cntblk[b * SEGS + 2 * tid + 1];
        int s = v0 + v1;
        int xx = s;
        #pragma unroll
        for (int d = 1; d < 64; d <<= 1) {         // inclusive shfl scan
            int y = __shfl_up(xx, d);
            if (tid >= d) xx += y;
        }
        int excl = xx - s;
        scnt[2 * tid] = v0;  scnt[2 * tid + 1] = v1;
        soff[2 * tid] = excl; soff[2 * tid + 1] = excl + v0;
        if (tid == 63) snv = xx;
    }
    __syncthreads();
    const int nv = snv;
    if (blockIdx.x == 0 && tid == 0) cnt[b] = nv;
    const int c0 = blockIdx.x * 64;
    if (c0 >= nv) return;                          // block-uniform exit

    // flat parallel pack: slot g=(s<<5)+j -> sk[soff[s]+j]; loads independent
    const unsigned long long* kb = gkeys + ((size_t)b << 12);
    #pragma unroll 4
    for (int g = tid; g < SEGS * SEGR; g += 256) {
        int s = g >> 5, j = g & 31;
        if (j < scnt[s]) sk[soff[s] + j] = kb[g];
    }
    if (tid == 0) { sk[nv] = ~0ull; sk[nv + 1] = ~0ull; }  // pair-read pad
    __syncthreads();

    const int li = tid & 63, q = tid >> 6;
    const int bi = c0 + li;
    const bool active = bi < nv;
    const unsigned long long myk = active ? sk[bi] : 0;
    const int P = (nv + 1) >> 1;                   // u64 pairs
    const int j0 = (P * q) >> 2, j1 = (P * (q + 1)) >> 2;
    const ulonglong2* skp = (const ulonglong2*)sk;
    int cr = 0;
    for (int j = j0; j < j1; ++j) {                // b128 broadcast reads
        ulonglong2 kk = skp[j];
        cr += (kk.x < myk) ? 1 : 0;
        cr += (kk.y < myk) ? 1 : 0;
    }
    part[tid] = cr;
    __syncthreads();
    if (q == 0 && active) {
        int rank = part[li] + part[li + 64] + part[li + 128] + part[li + 192];
        int idx = (int)((myk >> 7) & (N - 1));
        int s = (b << 12) + idx;
        int d = (b << 12) + rank;                  // exact stable rank
        rbox[d] = vbox[s];
        rco[d]  = vco[s];
        rcls[d] = (int)(myk & 127u);
    }
}

// ---------------- K3: per-(batch,class) greedy NMS + emit ----------------
// grid (NC, BS), one wave. 32 unrolled independent rcls chunk loads (one
// exposed latency) -> ballot compaction of member ranks; box gather in <=2
// scattered rounds; wave-synchronous greedy (reference IoU); direct row emit.
__global__ __launch_bounds__(64) void nms_kernel(
        const float4* __restrict__ rbox,
        const float2* __restrict__ rco,
        const int* __restrict__ rcls,
        const int* __restrict__ cnt,
        float4* __restrict__ out) {
    __shared__ float4 sbox[MC];
    __shared__ unsigned short srank[MC];
    __shared__ unsigned char srem[MC];
    const int c = blockIdx.x, b = blockIdx.y, lane = threadIdx.x;
    const int bN = b << 12;
    const int nv = cnt[b];
    constexpr int MAXCH = 32;                      // covers nv <= 2048 fast path

    int cv[MAXCH];
    #pragma unroll
    for (int ch = 0; ch < MAXCH; ++ch) {           // independent coalesced loads
        int rn = ch * 64 + lane;
        cv[ch] = rcls[bN + (rn < nv ? rn : 0)];    // clamped, in-bounds
    }
    int n = 0;
    #pragma unroll
    for (int ch = 0; ch < MAXCH; ++ch) {
        int rn = ch * 64 + lane;
        bool member = (rn < nv) && (cv[ch] == c);
        unsigned long long mb = __ballot(member);
        if (member) {
            int pos = n + __popcll(mb & ((1ull << lane) - 1ull));
            if (pos < MC) srank[pos] = (unsigned short)rn;
        }
        n += __popcll(mb);
    }
    for (int base = MAXCH * 64; base < nv; base += 64) {   // rare tail (nv>2048)
        int rn = base + lane;
        bool member = (rn < nv) && (rcls[bN + (rn < nv ? rn : 0)] == c);
        unsigned long long mb = __ballot(member);
        if (member) {
            int pos = n + __popcll(mb & ((1ull << lane) - 1ull));
            if (pos < MC) srank[pos] = (unsigned short)rn;
        }
        n += __popcll(mb);
    }
    if (n > MC) n = MC;
    const int m = n;

    // gather member boxes (rank order == conf-desc order), <=2 scattered rounds
    for (int i = lane; i < m; i += 64) {
        sbox[i] = rbox[bN + srank[i]];
        srem[i] = 0;
    }

    // single wave owns the LDS: wave-synchronous, no barriers needed
    for (int i = 0; i < m; ++i) {
        if (srem[i]) continue;                     // same LDS address: uniform
        float4 bi4 = sbox[i];
        float ai = (bi4.z - bi4.x) * (bi4.w - bi4.y);
        for (int j = i + 1 + lane; j < m; j += 64) {
            if (!srem[j]) {
                float4 bj = sbox[j];
                float ix1 = fmaxf(bi4.x, bj.x);
                float iy1 = fmaxf(bi4.y, bj.y);
                float ix2 = fminf(bi4.z, bj.z);
                float iy2 = fminf(bi4.w, bj.w);
                float inter = fmaxf(ix2 - ix1, 0.0f) * fmaxf(iy2 - iy1, 0.0f);
                float aj = (bj.z - bj.x) * (bj.w - bj.y);
                float iou = inter / (ai + aj - inter + 1e-16f);
                if (iou > NMS_T) srem[j] = 1;
            }
        }
    }
    for (int j = lane; j < m; j += 64) {
        if (!srem[j]) {
            int rr = srank[j];
            float4 bq = sbox[j];
            float2 oc = rco[bN + rr];
            float4* o = out + (size_t)(bN + rr) * 2;
            o[0] = make_float4((float)b, bq.x, bq.y, bq.z);
            o[1] = make_float4(bq.w, oc.x, oc.y, (float)c);
        }
    }
}

extern "C" void kernel_launch(void* const* d_in, const int* in_sizes, int n_in,
                              void* d_out, int out_size, void* d_ws, size_t ws_size,
                              hipStream_t stream) {
    const float* x = (const float*)d_in[0];
    float4* out = (float4*)d_out;

    char* ws = (char*)d_ws;
    size_t off = 0;
    auto alloc = [&](size_t bytes) { char* p = ws + off; off += (bytes + 255) & ~255ull; return p; };
    unsigned long long* gkeys = (unsigned long long*)alloc(BS * N * 8);  // 256 KB
    float4* vbox = (float4*)alloc(BS * N * 16);                           // 512 KB
    float2* vco  = (float2*)alloc(BS * N * 8);                            // 256 KB
    int*    cntblk = (int*)alloc(BS * SEGS * 4);                          // 4 KB
    float4* rbox = (float4*)alloc(BS * N * 16);                           // 512 KB
    float2* rco  = (float2*)alloc(BS * N * 8);                            // 256 KB
    int*    rcls = (int*)alloc(BS * N * 4);                               // 128 KB
    int*    cnt  = (int*)alloc(BS * 4);                                   // 32 B

    prep_kernel<<<BS * N / SEGR, 256, 0, stream>>>(x, gkeys, vbox, vco, cntblk, out);
    rank_kernel<<<dim3(64, BS), 256, 0, stream>>>(gkeys, vbox, vco, cntblk,
                                                  rbox, rco, rcls, cnt);
    nms_kernel<<<dim3(NC, BS), 64, 0, stream>>>(rbox, rco, rcls, cnt, out);
}

// Round 4
// 87.789 us; speedup vs baseline: 1.5084x; 1.0325x over previous
//
#include <hip/hip_runtime.h>

// Problem constants (reference: x = [8, 4096, 85] fp32)
constexpr int BS = 8;
constexpr int N  = 4096;
constexpr int F  = 85;
constexpr int NC = 80;          // classes = F - 5
constexpr float CONF_T = 0.65f;
constexpr float NMS_T  = 0.55f;
constexpr int MC   = 96;        // per-(batch,class) member cap (mean ~18, max ~33)
constexpr int SEGR = 32;        // rows per prep block / segment
constexpr int SEGS = N / SEGR;  // segments per batch = 128

// key = (~bits(conf))<<19 | idx<<7 | cls.  Ascending key order == (conf desc,
// idx asc) == the reference's stable argsort (idx unique -> cls bits never
// affect order). Only VALID boxes get keys (segmented compact layout).
//
// R4: measured kernel bodies are ~15us of the 90us window (R2/R3 delta
// analysis: non-prep time constant at ~82us while the 41.5us poison-fill +
// dozens of harness memsets + launch gaps fill the rest). Only controllable
// levers: launch count + marginal kernel time. So rank_kernel is fused into
// the per-class NMS kernel (3 -> 2 launches): each (c,b) block packs the
// segmented keys to LDS, ballot-detects its class members, and computes each
// member's exact global rank by a lane-per-member broadcast scan over the
// nv packed keys (split across 4 waves). Removes rank launch + gap + the
// rbox/rco/rcls round-trip. R2 lesson kept: zero global atomics.

// ---------------- K1: prep (LDS-staged read, 8-way argmax, segment compact) ----
__global__ __launch_bounds__(256) void prep_kernel(
        const float* __restrict__ x,
        unsigned long long* __restrict__ gkeys,   // [BS][SEGS*32] segmented
        float4* __restrict__ vbox,                // [BS*N] by original idx (valid only)
        float2* __restrict__ vco,                 // (obj, conf)
        int* __restrict__ cntblk,                 // [BS*SEGS]
        float4* __restrict__ out) {
    __shared__ __align__(16) float sx[SEGR * F];  // 10,880 B
    __shared__ int wq[4];
    const int tid = threadIdx.x, blk = blockIdx.x;
    const int row0 = blk * SEGR;
    const int b = blk >> 7;                       // blk / SEGS
    // coalesced staging: 680 float4 per block, 3 rounds
    const float4* src = (const float4*)(x + (size_t)row0 * F);
    float4* dst = (float4*)sx;
    constexpr int NV4 = SEGR * F / 4;             // 680
    for (int i = tid; i < NV4; i += 256) dst[i] = src[i];
    // zero this block's 32 output rows (2 float4 each, covered once per grid)
    if (tid < SEGR * 2)
        out[(size_t)row0 * 2 + tid] = make_float4(0.f, 0.f, 0.f, 0.f);
    __syncthreads();

    // split argmax: thread (r, h) scans classes h*10..h*10+9 of row r
    const int r = tid >> 3, h = tid & 7;
    float best; int bidx;
    {
        const float* p = sx + r * F + 5 + h * 10;
        float bv = p[0]; int bi = 0;
        #pragma unroll
        for (int c = 1; c < 10; ++c) {
            float v = p[c];
            if (v > bv) { bv = v; bi = c; }       // strict >: first max in chunk
        }
        best = bv; bidx = bi + h * 10;
    }
    // reduce across the 8 h-lanes (same wave, xor in low 3 bits of lane)
    #pragma unroll
    for (int d = 1; d < 8; d <<= 1) {
        float ov = __shfl_xor(best, d);
        int   oi = __shfl_xor(bidx, d);
        if (ov > best || (ov == best && oi < bidx)) { best = ov; bidx = oi; }
    }   // == global max with smallest attaining idx == jnp.argmax (first max)

    bool valid = false;
    unsigned long long key = 0;
    if (h == 0) {
        const float* p = sx + r * F;
        float obj = p[4];
        valid = obj > CONF_T;
        const int t = row0 + r;
        if (valid) {
            float cx = p[0], cy = p[1], w = p[2], hh = p[3];
            vbox[t] = make_float4(cx - w * 0.5f, cy - hh * 0.5f,
                                  cx + w * 0.5f, cy + hh * 0.5f);
            vco[t]  = make_float2(obj, best);
            key = ((unsigned long long)(~__float_as_uint(best)) << 19)
                | ((unsigned long long)(unsigned)(t & (N - 1)) << 7)
                | (unsigned)bidx;
        }
    }
    // deterministic block-local compaction into this block's 32-slot segment
    const int lane = tid & 63, w = tid >> 6;
    unsigned long long mask = __ballot(valid);
    if (lane == 0) wq[w] = __popcll(mask);
    __syncthreads();
    int base = 0;
    for (int i = 0; i < w; ++i) base += wq[i];
    if (valid) {
        int slot = base + __popcll(mask & ((1ull << lane) - 1ull));
        gkeys[((size_t)b << 12) + ((blk & (SEGS - 1)) << 5) + slot] = key;
    }
    if (tid == 0) cntblk[blk] = wq[0] + wq[1] + wq[2] + wq[3];
}

// ---------------- K2: fused per-(batch,class) rank + greedy NMS + emit --------
// grid (NC, BS) x 256.  Phases (4 waves):
//   1. wave0: shfl scan of 128 segment counts -> scnt/soff/nv
//   2. all:   batched coalesced gkeys loads, predicated pack -> sk[nv] in LDS
//   3. wave0: ballot member-detect (cls==c) -> skm[m] (key list, idx order)
//   4. all:   lane-per-member global rank: broadcast b128 scan of sk, quarter
//             per wave, partials in LDS
//   5. wave0: reduce ranks; within-class order via m-loop; permute to sorted
//             LDS slots; wave-synchronous greedy NMS; emit at global-rank row.
__global__ __launch_bounds__(256) void cnms_kernel(
        const unsigned long long* __restrict__ gkeys,
        const float4* __restrict__ vbox,
        const float2* __restrict__ vco,
        const int* __restrict__ cntblk,
        float4* __restrict__ out) {
    __shared__ __align__(16) unsigned long long sk[N + 2];  // 32,784 B
    __shared__ int scnt[SEGS];
    __shared__ int soff[SEGS];
    __shared__ int snv, sm;
    __shared__ unsigned long long skm[MC];
    __shared__ int2 spart[256];
    __shared__ float4 sbox[MC];
    __shared__ float2 sco[MC];
    __shared__ int sgrk[MC];
    __shared__ unsigned char srem[MC];
    const int c = blockIdx.x, b = blockIdx.y, tid = threadIdx.x;
    const int bN = b << 12;
    const int li = tid & 63, q = tid >> 6;

    // --- phase 1: segment-count scan (wave 0, 2 counts/lane) ---
    if (tid < 64) {
        int v0 = cntblk[b * SEGS + 2 * tid];
        int v1 = cntblk[b * SEGS + 2 * tid + 1];
        int s = v0 + v1;
        int xx = s;
        #pragma unroll
        for (int d = 1; d < 64; d <<= 1) {
            int y = __shfl_up(xx, d);
            if (tid >= d) xx += y;
        }
        int excl = xx - s;
        scnt[2 * tid] = v0;  scnt[2 * tid + 1] = v1;
        soff[2 * tid] = excl; soff[2 * tid + 1] = excl + v0;
        if (tid == 63) snv = xx;
    }
    __syncthreads();
    const int nv = snv;

    // --- phase 2: pack segmented keys -> sk[0..nv) (batched loads) ---
    const unsigned long long* kb = gkeys + ((size_t)b << 12);
    #pragma unroll
    for (int r = 0; r < 4; ++r) {                  // 16 slots/thread, batch 4
        unsigned long long v[4]; int gg[4];
        #pragma unroll
        for (int qq = 0; qq < 4; ++qq) { gg[qq] = tid + (r * 4 + qq) * 256; v[qq] = kb[gg[qq]]; }
        #pragma unroll
        for (int qq = 0; qq < 4; ++qq) {
            int s = gg[qq] >> 5, j = gg[qq] & 31;
            if (j < scnt[s]) sk[soff[s] + j] = v[qq];
        }
    }
    if (tid == 0) { sk[nv] = ~0ull; sk[nv + 1] = ~0ull; }  // pair-read pad
    __syncthreads();

    // --- phase 3: member detect (wave 0, wave-synchronous) ---
    if (tid < 64) {
        int mcount = 0;
        const int nch = (nv + 63) >> 6;
        for (int rc = 0; rc < nch; ++rc) {
            int j = (rc << 6) + tid;
            unsigned long long k = sk[j];          // in-bounds (size N+2)
            bool member = (j < nv) && ((int)(k & 127u) == c);
            unsigned long long mb = __ballot(member);
            if (member) {
                int pos = mcount + __popcll(mb & ((1ull << tid) - 1ull));
                if (pos < MC) skm[pos] = k;
            }
            mcount += __popcll(mb);
        }
        if (tid == 0) sm = (mcount < MC) ? mcount : MC;
    }
    __syncthreads();
    const int m = sm;
    if (m == 0) return;                            // uniform across block

    // --- phase 4: global rank scan (lane-per-member, quarter per wave) ---
    const unsigned long long mk0 = (li < m)      ? skm[li]      : ~0ull;
    const unsigned long long mk1 = (64 + li < m) ? skm[64 + li] : ~0ull;
    const int P = (nv + 1) >> 1;                   // u64 pairs
    const int j0 = (P * q) >> 2, j1 = (P * (q + 1)) >> 2;
    const ulonglong2* skp = (const ulonglong2*)sk;
    int cr0 = 0, cr1 = 0;
    if (m > 64) {                                  // uniform branch (rare)
        for (int j = j0; j < j1; ++j) {
            ulonglong2 kk = skp[j];
            cr0 += (kk.x < mk0) + (kk.y < mk0);
            cr1 += (kk.x < mk1) + (kk.y < mk1);
        }
    } else {
        for (int j = j0; j < j1; ++j) {            // b128 broadcast reads
            ulonglong2 kk = skp[j];
            cr0 += (kk.x < mk0) + (kk.y < mk0);
        }
    }
    spart[tid] = make_int2(cr0, cr1);
    __syncthreads();

    // --- phase 5: reduce, sort-permute, greedy NMS, emit (wave 0) ---
    if (tid < 64) {
        if (li < m) {
            int grk = spart[li].x + spart[64 + li].x
                    + spart[128 + li].x + spart[192 + li].x;
            int wrk = 0;                           // within-class (conf-desc) slot
            for (int i2 = 0; i2 < m; ++i2) wrk += (skm[i2] < mk0);
            int idx = (int)((mk0 >> 7) & (N - 1));
            sbox[wrk] = vbox[bN + idx];
            sco[wrk]  = vco[bN + idx];
            sgrk[wrk] = grk;
            srem[wrk] = 0;
        }
        if (m > 64 && 64 + li < m) {               // second member slot (rare)
            int grk = spart[li].y + spart[64 + li].y
                    + spart[128 + li].y + spart[192 + li].y;
            int wrk = 0;
            for (int i2 = 0; i2 < m; ++i2) wrk += (skm[i2] < mk1);
            int idx = (int)((mk1 >> 7) & (N - 1));
            sbox[wrk] = vbox[bN + idx];
            sco[wrk]  = vco[bN + idx];
            sgrk[wrk] = grk;
            srem[wrk] = 0;
        }
        // wave-synchronous greedy (reference IoU), members in conf-desc order
        for (int i = 0; i < m; ++i) {
            if (srem[i]) continue;                 // same LDS address: uniform
            float4 bi4 = sbox[i];
            float ai = (bi4.z - bi4.x) * (bi4.w - bi4.y);
            for (int j = i + 1 + li; j < m; j += 64) {
                if (!srem[j]) {
                    float4 bj = sbox[j];
                    float ix1 = fmaxf(bi4.x, bj.x);
                    float iy1 = fmaxf(bi4.y, bj.y);
                    float ix2 = fminf(bi4.z, bj.z);
                    float iy2 = fminf(bi4.w, bj.w);
                    float inter = fmaxf(ix2 - ix1, 0.0f) * fmaxf(iy2 - iy1, 0.0f);
                    float aj = (bj.z - bj.x) * (bj.w - bj.y);
                    float iou = inter / (ai + aj - inter + 1e-16f);
                    if (iou > NMS_T) srem[j] = 1;
                }
            }
        }
        for (int j = li; j < m; j += 64) {
            if (!srem[j]) {
                float4 bq = sbox[j];
                float2 oc = sco[j];
                float4* o = out + (size_t)(bN + sgrk[j]) * 2;
                o[0] = make_float4((float)b, bq.x, bq.y, bq.z);
                o[1] = make_float4(bq.w, oc.x, oc.y, (float)c);
            }
        }
    }
}

extern "C" void kernel_launch(void* const* d_in, const int* in_sizes, int n_in,
                              void* d_out, int out_size, void* d_ws, size_t ws_size,
                              hipStream_t stream) {
    const float* x = (const float*)d_in[0];
    float4* out = (float4*)d_out;

    char* ws = (char*)d_ws;
    size_t off = 0;
    auto alloc = [&](size_t bytes) { char* p = ws + off; off += (bytes + 255) & ~255ull; return p; };
    unsigned long long* gkeys = (unsigned long long*)alloc(BS * N * 8);  // 256 KB
    float4* vbox = (float4*)alloc(BS * N * 16);                           // 512 KB
    float2* vco  = (float2*)alloc(BS * N * 8);                            // 256 KB
    int*    cntblk = (int*)alloc(BS * SEGS * 4);                          // 4 KB

    prep_kernel<<<BS * N / SEGR, 256, 0, stream>>>(x, gkeys, vbox, vco, cntblk, out);
    cnms_kernel<<<dim3(NC, BS), 256, 0, stream>>>(gkeys, vbox, vco, cntblk, out);
}

// Round 5
// 85.387 us; speedup vs baseline: 1.5508x; 1.0281x over previous
//
#include <hip/hip_runtime.h>

// Problem constants (reference: x = [8, 4096, 85] fp32)
constexpr int BS = 8;
constexpr int N  = 4096;
constexpr int F  = 85;
constexpr int NC = 80;          // classes = F - 5
constexpr float CONF_T = 0.65f;
constexpr float NMS_T  = 0.55f;
constexpr int MC   = 96;        // per-(batch,class) member cap (mean ~18, max ~33)
constexpr int SEGR = 32;        // rows per prep block / segment
constexpr int SEGS = N / SEGR;  // segments per batch = 128

// key = (~bits(conf))<<19 | idx<<7 | cls.  Ascending key order == (conf desc,
// idx asc) == the reference's stable argsort (idx unique -> cls bits never
// affect order). Only VALID boxes get keys (segmented compact layout).
//
// Budget model (R2..R4 deltas): window = ~43us harness poison-fill +
// ~25-35us harness memsets/launch gaps + ~7-12us our kernel bodies.
// Launch gap + small body ~= 3us (R3->R4). R5 trims cnms's critical path:
//  (a) issue all 8 b128 gkey loads BEFORE the wave0 cntblk scan (L2 latency
//      hides under scan+barrier; addresses are static),
//  (b) dual-ballot member detect: 128 keys/iter instead of 64 (order kept).
// prep byte-identical to R3 (no counter evidence against it).

// ---------------- K1: prep (LDS-staged read, 8-way argmax, segment compact) ----
__global__ __launch_bounds__(256) void prep_kernel(
        const float* __restrict__ x,
        unsigned long long* __restrict__ gkeys,   // [BS][SEGS*32] segmented
        float4* __restrict__ vbox,                // [BS*N] by original idx (valid only)
        float2* __restrict__ vco,                 // (obj, conf)
        int* __restrict__ cntblk,                 // [BS*SEGS]
        float4* __restrict__ out) {
    __shared__ __align__(16) float sx[SEGR * F];  // 10,880 B
    __shared__ int wq[4];
    const int tid = threadIdx.x, blk = blockIdx.x;
    const int row0 = blk * SEGR;
    const int b = blk >> 7;                       // blk / SEGS
    // coalesced staging: 680 float4 per block, 3 rounds
    const float4* src = (const float4*)(x + (size_t)row0 * F);
    float4* dst = (float4*)sx;
    constexpr int NV4 = SEGR * F / 4;             // 680
    for (int i = tid; i < NV4; i += 256) dst[i] = src[i];
    // zero this block's 32 output rows (2 float4 each, covered once per grid)
    if (tid < SEGR * 2)
        out[(size_t)row0 * 2 + tid] = make_float4(0.f, 0.f, 0.f, 0.f);
    __syncthreads();

    // split argmax: thread (r, h) scans classes h*10..h*10+9 of row r
    const int r = tid >> 3, h = tid & 7;
    float best; int bidx;
    {
        const float* p = sx + r * F + 5 + h * 10;
        float bv = p[0]; int bi = 0;
        #pragma unroll
        for (int c = 1; c < 10; ++c) {
            float v = p[c];
            if (v > bv) { bv = v; bi = c; }       // strict >: first max in chunk
        }
        best = bv; bidx = bi + h * 10;
    }
    // reduce across the 8 h-lanes (same wave, xor in low 3 bits of lane)
    #pragma unroll
    for (int d = 1; d < 8; d <<= 1) {
        float ov = __shfl_xor(best, d);
        int   oi = __shfl_xor(bidx, d);
        if (ov > best || (ov == best && oi < bidx)) { best = ov; bidx = oi; }
    }   // == global max with smallest attaining idx == jnp.argmax (first max)

    bool valid = false;
    unsigned long long key = 0;
    if (h == 0) {
        const float* p = sx + r * F;
        float obj = p[4];
        valid = obj > CONF_T;
        const int t = row0 + r;
        if (valid) {
            float cx = p[0], cy = p[1], w = p[2], hh = p[3];
            vbox[t] = make_float4(cx - w * 0.5f, cy - hh * 0.5f,
                                  cx + w * 0.5f, cy + hh * 0.5f);
            vco[t]  = make_float2(obj, best);
            key = ((unsigned long long)(~__float_as_uint(best)) << 19)
                | ((unsigned long long)(unsigned)(t & (N - 1)) << 7)
                | (unsigned)bidx;
        }
    }
    // deterministic block-local compaction into this block's 32-slot segment
    const int lane = tid & 63, w = tid >> 6;
    unsigned long long mask = __ballot(valid);
    if (lane == 0) wq[w] = __popcll(mask);
    __syncthreads();
    int base = 0;
    for (int i = 0; i < w; ++i) base += wq[i];
    if (valid) {
        int slot = base + __popcll(mask & ((1ull << lane) - 1ull));
        gkeys[((size_t)b << 12) + ((blk & (SEGS - 1)) << 5) + slot] = key;
    }
    if (tid == 0) cntblk[blk] = wq[0] + wq[1] + wq[2] + wq[3];
}

// ---------------- K2: fused per-(batch,class) rank + greedy NMS + emit --------
// grid (NC, BS) x 256.  Phases:
//   0. all:   issue 8 b128 gkey loads (static addrs; latency hides under 1.)
//   1. wave0: shfl scan of 128 segment counts -> scnt/soff/nv
//   2. all:   predicated pack of loaded keys -> sk[nv] in LDS
//   3. wave0: dual-ballot member-detect (128 keys/iter) -> skm[m]
//   4. all:   lane-per-member global rank: broadcast b128 scan of sk, quarter
//             per wave, partials in LDS
//   5. wave0: reduce ranks; within-class order via key-compare; greedy NMS;
//             emit at global-rank row.
__global__ __launch_bounds__(256) void cnms_kernel(
        const unsigned long long* __restrict__ gkeys,
        const float4* __restrict__ vbox,
        const float2* __restrict__ vco,
        const int* __restrict__ cntblk,
        float4* __restrict__ out) {
    __shared__ __align__(16) unsigned long long sk[N + 130]; // 33.8 KB (+dual-ballot margin)
    __shared__ int scnt[SEGS];
    __shared__ int soff[SEGS];
    __shared__ int snv, sm;
    __shared__ unsigned long long skm[MC];
    __shared__ int2 spart[256];
    __shared__ float4 sbox[MC];
    __shared__ float2 sco[MC];
    __shared__ int sgrk[MC];
    __shared__ unsigned char srem[MC];
    const int c = blockIdx.x, b = blockIdx.y, tid = threadIdx.x;
    const int bN = b << 12;
    const int li = tid & 63, q = tid >> 6;

    // --- phase 0: issue all key loads (b128, coalesced; L2-resident) ---
    const unsigned long long* kb = gkeys + ((size_t)b << 12);
    const ulonglong2* kb2 = (const ulonglong2*)kb;
    ulonglong2 v[8];
    #pragma unroll
    for (int r = 0; r < 8; ++r) v[r] = kb2[tid + r * 256];

    // --- phase 1: segment-count scan (wave 0, 2 counts/lane) ---
    if (tid < 64) {
        int v0 = cntblk[b * SEGS + 2 * tid];
        int v1 = cntblk[b * SEGS + 2 * tid + 1];
        int s = v0 + v1;
        int xx = s;
        #pragma unroll
        for (int d = 1; d < 64; d <<= 1) {
            int y = __shfl_up(xx, d);
            if (tid >= d) xx += y;
        }
        int excl = xx - s;
        scnt[2 * tid] = v0;  scnt[2 * tid + 1] = v1;
        soff[2 * tid] = excl; soff[2 * tid + 1] = excl + v0;
        if (tid == 63) snv = xx;
    }
    __syncthreads();
    const int nv = snv;

    // --- phase 2: predicated pack -> sk[0..nv) ---
    #pragma unroll
    for (int r = 0; r < 8; ++r) {
        int s0 = (tid + r * 256) << 1;             // even slot
        int s = s0 >> 5, j = s0 & 31;              // j even, j+1 in same segment
        int cn = scnt[s], of = soff[s];
        if (j < cn)     sk[of + j]     = v[r].x;
        if (j + 1 < cn) sk[of + j + 1] = v[r].y;
    }
    if (tid == 0) { sk[nv] = ~0ull; sk[nv + 1] = ~0ull; }  // pair-read pad
    __syncthreads();

    // --- phase 3: dual-ballot member detect (wave 0, 128 keys/iter) ---
    if (tid < 64) {
        int mcount = 0;
        const int nch = (nv + 127) >> 7;
        for (int rc = 0; rc < nch; ++rc) {
            int j0i = (rc << 7) + tid;
            unsigned long long k0 = sk[j0i];       // in-bounds (size N+130)
            unsigned long long k1 = sk[j0i + 64];
            bool m0 = (j0i < nv)      && ((int)(k0 & 127u) == c);
            bool m1 = (j0i + 64 < nv) && ((int)(k1 & 127u) == c);
            unsigned long long mb0 = __ballot(m0);
            unsigned long long mb1 = __ballot(m1);
            if (m0) {
                int pos = mcount + __popcll(mb0 & ((1ull << tid) - 1ull));
                if (pos < MC) skm[pos] = k0;
            }
            int n0 = __popcll(mb0);
            if (m1) {
                int pos = mcount + n0 + __popcll(mb1 & ((1ull << tid) - 1ull));
                if (pos < MC) skm[pos] = k1;
            }
            mcount += n0 + __popcll(mb1);
        }
        if (tid == 0) sm = (mcount < MC) ? mcount : MC;
    }
    __syncthreads();
    const int m = sm;
    if (m == 0) return;                            // uniform across block

    // --- phase 4: global rank scan (lane-per-member, quarter per wave) ---
    const unsigned long long mk0 = (li < m)      ? skm[li]      : ~0ull;
    const unsigned long long mk1 = (64 + li < m) ? skm[64 + li] : ~0ull;
    const int P = (nv + 1) >> 1;                   // u64 pairs
    const int j0 = (P * q) >> 2, j1 = (P * (q + 1)) >> 2;
    const ulonglong2* skp = (const ulonglong2*)sk;
    int cr0 = 0, cr1 = 0;
    if (m > 64) {                                  // uniform branch (rare)
        for (int j = j0; j < j1; ++j) {
            ulonglong2 kk = skp[j];
            cr0 += (kk.x < mk0) + (kk.y < mk0);
            cr1 += (kk.x < mk1) + (kk.y < mk1);
        }
    } else {
        for (int j = j0; j < j1; ++j) {            // b128 broadcast reads
            ulonglong2 kk = skp[j];
            cr0 += (kk.x < mk0) + (kk.y < mk0);
        }
    }
    spart[tid] = make_int2(cr0, cr1);
    __syncthreads();

    // --- phase 5: reduce, sort-permute, greedy NMS, emit (wave 0) ---
    if (tid < 64) {
        if (li < m) {
            int grk = spart[li].x + spart[64 + li].x
                    + spart[128 + li].x + spart[192 + li].x;
            int wrk = 0;                           // within-class (conf-desc) slot
            for (int i2 = 0; i2 < m; ++i2) wrk += (skm[i2] < mk0);
            int idx = (int)((mk0 >> 7) & (N - 1));
            sbox[wrk] = vbox[bN + idx];
            sco[wrk]  = vco[bN + idx];
            sgrk[wrk] = grk;
            srem[wrk] = 0;
        }
        if (m > 64 && 64 + li < m) {               // second member slot (rare)
            int grk = spart[li].y + spart[64 + li].y
                    + spart[128 + li].y + spart[192 + li].y;
            int wrk = 0;
            for (int i2 = 0; i2 < m; ++i2) wrk += (skm[i2] < mk1);
            int idx = (int)((mk1 >> 7) & (N - 1));
            sbox[wrk] = vbox[bN + idx];
            sco[wrk]  = vco[bN + idx];
            sgrk[wrk] = grk;
            srem[wrk] = 0;
        }
        // wave-synchronous greedy (reference IoU), members in conf-desc order
        for (int i = 0; i < m; ++i) {
            if (srem[i]) continue;                 // same LDS address: uniform
            float4 bi4 = sbox[i];
            float ai = (bi4.z - bi4.x) * (bi4.w - bi4.y);
            for (int j = i + 1 + li; j < m; j += 64) {
                if (!srem[j]) {
                    float4 bj = sbox[j];
                    float ix1 = fmaxf(bi4.x, bj.x);
                    float iy1 = fmaxf(bi4.y, bj.y);
                    float ix2 = fminf(bi4.z, bj.z);
                    float iy2 = fminf(bi4.w, bj.w);
                    float inter = fmaxf(ix2 - ix1, 0.0f) * fmaxf(iy2 - iy1, 0.0f);
                    float aj = (bj.z - bj.x) * (bj.w - bj.y);
                    float iou = inter / (ai + aj - inter + 1e-16f);
                    if (iou > NMS_T) srem[j] = 1;
                }
            }
        }
        for (int j = li; j < m; j += 64) {
            if (!srem[j]) {
                float4 bq = sbox[j];
                float2 oc = sco[j];
                float4* o = out + (size_t)(bN + sgrk[j]) * 2;
                o[0] = make_float4((float)b, bq.x, bq.y, bq.z);
                o[1] = make_float4(bq.w, oc.x, oc.y, (float)c);
            }
        }
    }
}

extern "C" void kernel_launch(void* const* d_in, const int* in_sizes, int n_in,
                              void* d_out, int out_size, void* d_ws, size_t ws_size,
                              hipStream_t stream) {
    const float* x = (const float*)d_in[0];
    float4* out = (float4*)d_out;

    char* ws = (char*)d_ws;
    size_t off = 0;
    auto alloc = [&](size_t bytes) { char* p = ws + off; off += (bytes + 255) & ~255ull; return p; };
    unsigned long long* gkeys = (unsigned long long*)alloc(BS * N * 8);  // 256 KB
    float4* vbox = (float4*)alloc(BS * N * 16);                           // 512 KB
    float2* vco  = (float2*)alloc(BS * N * 8);                            // 256 KB
    int*    cntblk = (int*)alloc(BS * SEGS * 4);                          // 4 KB

    prep_kernel<<<BS * N / SEGR, 256, 0, stream>>>(x, gkeys, vbox, vco, cntblk, out);
    cnms_kernel<<<dim3(NC, BS), 256, 0, stream>>>(gkeys, vbox, vco, cntblk, out);
}